// Round 5
// baseline (407.443 us; speedup 1.0000x reference)
//
#include <hip/hip_runtime.h>

typedef unsigned short ushort_t;
typedef unsigned int uint_t;
typedef __attribute__((ext_vector_type(8))) short bf16x8;
typedef __attribute__((ext_vector_type(4))) float f32x4;
typedef __attribute__((ext_vector_type(2))) float f32x2;

#define N_NODES 50000
#define N_EDGES 800000
#define BN_EPS 1e-5f

// ws layout (floats): [0 .. 4800000) h buffer   [4800000..4801536) BN stats
//                     (8 replicas x 192)        [4801536] edge dtype flag
#define OFF_STATS 4800000
#define OFF_FLAG  4801536
#define NREP 8

// scratch carved out of d_out (ints) — consumed before bn writes out:
#define SC_PAIR  0        // int2[800000]  (eid, src) sorted by dst
#define SC_LEXCL 1600000  // int[50000]  block-local exclusive prefix of deg
#define SC_DEG   1650016  // int[50000]
#define SC_RANK  1700032  // int[800000]
#define SC_BSUM  2500032  // int[196]    per-256-chunk degree totals

#define NB_SCAN 196  // ceil(50000/256)
#define MTILE 64
#define NTILES ((N_NODES + MTILE - 1) / MTILE)  // 782

__device__ __forceinline__ ushort_t f2bf(float f) {
    uint_t u = __float_as_uint(f);
    uint_t r = ((u >> 16) & 1u) + 0x7fffu;  // RNE
    return (ushort_t)((u + r) >> 16);
}

// ---------------------------------------------------------------------------
// init: zero deg + stats replicas; block 0 detects int64 vs int32 edge_index.
// ---------------------------------------------------------------------------
__global__ __launch_bounds__(256) void init_kernel(const int* __restrict__ ei,
                                                   int* __restrict__ flag,
                                                   int* __restrict__ deg,
                                                   float* __restrict__ stats) {
    const int gtid = blockIdx.x * 256 + threadIdx.x;
    const int nth = gridDim.x * 256;
    for (int i = gtid; i < N_NODES; i += nth) deg[i] = 0;
    if (gtid < NREP * 192) stats[gtid] = 0.f;
    if (blockIdx.x == 0) {
        __shared__ int s_any;
        if (threadIdx.x == 0) s_any = 0;
        __syncthreads();
        int nz = 0;
#pragma unroll
        for (int j = 0; j < 16; ++j) {
            const int p = 1 + 2 * (threadIdx.x * 16 + j) * 195;  // odd, <1.6M
            if (ei[p] != 0) nz = 1;
        }
        if (nz) atomicOr(&s_any, 1);
        __syncthreads();
        if (threadIdx.x == 0) *flag = s_any ? 0 : 1;
    }
}

// ---------------------------------------------------------------------------
// hist: rank[e] = old deg[dst]++ (rank within dst bucket).
// ---------------------------------------------------------------------------
__global__ __launch_bounds__(256) void hist_kernel(const int* __restrict__ ei,
                                                   const int* __restrict__ flag,
                                                   int* __restrict__ deg,
                                                   int* __restrict__ rank) {
    const int is64 = *flag;
    const int stride = gridDim.x * blockDim.x;
    for (int e = blockIdx.x * blockDim.x + threadIdx.x; e < N_EDGES; e += stride) {
        int s, d;
        if (is64) { s = ei[2 * e]; d = ei[2 * N_EDGES + 2 * e]; }
        else      { s = ei[e];     d = ei[N_EDGES + e]; }
        if ((uint_t)s < N_NODES && (uint_t)d < N_NODES)
            rank[e] = atomicAdd(&deg[d], 1);
    }
}

// ---------------------------------------------------------------------------
// scanA: per-256-chunk scan. lexcl[i] = exclusive prefix within chunk,
// bsum[chunk] = chunk total. Consumers rebuild the 196-entry base scan in LDS.
// ---------------------------------------------------------------------------
__global__ __launch_bounds__(256) void scanA_kernel(const int* __restrict__ deg,
                                                    int* __restrict__ lexcl,
                                                    int* __restrict__ bsum) {
    __shared__ int sd[256];
    const int tid = threadIdx.x;
    const int i = blockIdx.x * 256 + tid;
    const int v = (i < N_NODES) ? deg[i] : 0;
    sd[tid] = v;
    __syncthreads();
    for (int off = 1; off < 256; off <<= 1) {
        int u = (tid >= off) ? sd[tid - off] : 0;
        __syncthreads();
        sd[tid] += u;
        __syncthreads();
    }
    if (i < N_NODES) lexcl[i] = sd[tid] - v;
    if (tid == 255) bsum[blockIdx.x] = sd[255];
}

__device__ __forceinline__ void build_sbase(const int* __restrict__ bsum,
                                            int* sd, int* sbase, int* tot) {
    const int tid = threadIdx.x;
    const int v = (tid < NB_SCAN) ? bsum[tid] : 0;
    sd[tid] = v;
    __syncthreads();
    for (int off = 1; off < 256; off <<= 1) {
        int u = (tid >= off) ? sd[tid - off] : 0;
        __syncthreads();
        sd[tid] += u;
        __syncthreads();
    }
    if (tid < NB_SCAN) sbase[tid] = sd[tid] - v;
    if (tid == NB_SCAN - 1) *tot = sd[tid];
    __syncthreads();
}

// ---------------------------------------------------------------------------
// scatter (atomic-free): pos = sbase[d>>8] + lexcl[d] + rank[e].
// ---------------------------------------------------------------------------
__global__ __launch_bounds__(256) void scatter_kernel(const int* __restrict__ ei,
                                                      const int* __restrict__ flag,
                                                      const int* __restrict__ lexcl,
                                                      const int* __restrict__ bsum,
                                                      const int* __restrict__ rank,
                                                      int2* __restrict__ pair) {
    __shared__ int sd[256];
    __shared__ int sbase[NB_SCAN];
    __shared__ int tot;
    build_sbase(bsum, sd, sbase, &tot);

    const int is64 = *flag;
    const int stride = gridDim.x * blockDim.x;
    for (int e = blockIdx.x * blockDim.x + threadIdx.x; e < N_EDGES; e += stride) {
        int s, d;
        if (is64) { s = ei[2 * e]; d = ei[2 * N_EDGES + 2 * e]; }
        else      { s = ei[e];     d = ei[N_EDGES + e]; }
        if ((uint_t)s < N_NODES && (uint_t)d < N_NODES) {
            const int pos = sbase[d >> 8] + lexcl[d] + rank[e];
            pair[pos] = make_int2(e, s);
        }
    }
}

// ---------------------------------------------------------------------------
// node_aggr over node range [n0, n1): one wave per node. Per 16-edge chunk:
//   proj[16e x 96f] = ea[eids] @ We via 6x mfma 16x16x32 bf16
//   (A[m=t][k=q*8+j], C row m=q*4+r col t  [m89 layout])
//   part[f] += relu(proj + be + x[src]); butterfly across quads; plain store.
// ---------------------------------------------------------------------------
__global__ __launch_bounds__(256) void node_aggr_kernel(
    const float* __restrict__ x, const float* __restrict__ ea,
    const float* __restrict__ We, const float* __restrict__ be,
    const int2* __restrict__ pair, const int* __restrict__ lexcl,
    const int* __restrict__ bsum, float* __restrict__ hbuf,
    int n0, int n1) {
    __shared__ int sd[256];
    __shared__ int sbase[NB_SCAN];
    __shared__ int tot;
    build_sbase(bsum, sd, sbase, &tot);

    const int lane = threadIdx.x & 63;
    const int q = lane >> 4;
    const int t = lane & 15;
    const int wav = blockIdx.x * 4 + (threadIdx.x >> 6);
    const int nwav = gridDim.x * 4;

    bf16x8 Bf[6];
    float ben[6];
#pragma unroll
    for (int f = 0; f < 6; ++f) {
        const int n = t + 16 * f;
#pragma unroll
        for (int j = 0; j < 8; ++j) {
            const int k = q * 8 + j;
            Bf[f][j] = (short)f2bf(We[k * 96 + n]);
        }
        ben[f] = be[n];
    }

    for (int n = n0 + wav; n < n1; n += nwav) {
        const int off = sbase[n >> 8] + lexcl[n];
        const int offn = (n + 1 == N_NODES) ? tot
                         : sbase[(n + 1) >> 8] + lexcl[n + 1];
        const int deg = offn - off;

        float part[6];
#pragma unroll
        for (int f = 0; f < 6; ++f) part[f] = 0.f;

        for (int c0 = 0; c0 < deg; c0 += 16) {
            const int rem = deg - c0;
            int eid_t = -1, src_t = -1;
            if (t < rem) {
                const int2 p = pair[off + c0 + t];
                eid_t = p.x;
                src_t = p.y;
            }
            bf16x8 A = {0, 0, 0, 0, 0, 0, 0, 0};
            if (eid_t >= 0) {
                const float* row = ea + (size_t)eid_t * 32 + q * 8;
                f32x4 a0 = *(const f32x4*)(row);
                f32x4 a1 = *(const f32x4*)(row + 4);
#pragma unroll
                for (int j = 0; j < 4; ++j) {
                    A[j] = (short)f2bf(a0[j]);
                    A[4 + j] = (short)f2bf(a1[j]);
                }
            }

            f32x4 acc[6];
#pragma unroll
            for (int f = 0; f < 6; ++f) {
                f32x4 z = {0.f, 0.f, 0.f, 0.f};
                acc[f] = __builtin_amdgcn_mfma_f32_16x16x32_bf16(A, Bf[f], z, 0, 0, 0);
            }

            int s_r[4];
#pragma unroll
            for (int r = 0; r < 4; ++r) s_r[r] = __shfl(src_t, q * 4 + r);

#pragma unroll
            for (int r = 0; r < 4; ++r) {
                const int m = q * 4 + r;
                if (m < rem) {
                    const float* xrow = x + (size_t)s_r[r] * 96;
#pragma unroll
                    for (int f = 0; f < 6; ++f) {
                        float v = acc[f][r] + ben[f] + xrow[t + 16 * f];
                        part[f] += v > 0.f ? v : 0.f;
                    }
                }
            }
        }

#pragma unroll
        for (int f = 0; f < 6; ++f) {
            part[f] += __shfl_xor(part[f], 16);
            part[f] += __shfl_xor(part[f], 32);
        }

        if (q == 0) {
            const float* xn = x + (size_t)n * 96;
            float* hn = hbuf + (size_t)n * 96;
#pragma unroll
            for (int f = 0; f < 6; ++f) {
                const int col = t + 16 * f;
                hn[col] = part[f] + xn[col];
            }
        }
    }
}

// ---------------------------------------------------------------------------
// mlp (tile range [tb, te)): 64-node tile, 256 threads, fp32 register-tiled.
// stats atomics striped over NREP replicas to break line contention.
// ---------------------------------------------------------------------------
__global__ __launch_bounds__(256) void mlp_kernel(
    float* buf, const float* __restrict__ W1g, const float* __restrict__ b1g,
    const float* __restrict__ W2g, const float* __restrict__ b2g,
    float* __restrict__ stats, int tb) {
    __shared__ float Ws[96 * 96];
    __shared__ float hsT[96][68];

    const int tid = threadIdx.x;
    const int fg = tid & 15;
    const int ng = tid >> 4;
    const int n0 = (tb + blockIdx.x) * MTILE;

    for (int i = tid; i < 96 * 96 / 4; i += 256)
        ((f32x4*)Ws)[i] = ((const f32x4*)W1g)[i];
    for (int i = tid; i < MTILE * 96 / 4; i += 256) {
        const int base = i * 4;
        const int nn = base / 96, k = base - nn * 96;
        f32x4 v = {0.f, 0.f, 0.f, 0.f};
        if (n0 + nn < N_NODES)
            v = *(const f32x4*)(buf + (size_t)(n0 + nn) * 96 + k);
        hsT[k][nn] = v[0]; hsT[k + 1][nn] = v[1];
        hsT[k + 2][nn] = v[2]; hsT[k + 3][nn] = v[3];
    }
    __syncthreads();

    float acc[4][6];
#pragma unroll
    for (int ff = 0; ff < 6; ++ff) {
        const float b = b1g[6 * fg + ff];
        acc[0][ff] = b; acc[1][ff] = b; acc[2][ff] = b; acc[3][ff] = b;
    }
    for (int k = 0; k < 96; ++k) {
        const f32x4 a = *(const f32x4*)&hsT[k][4 * ng];
        const float* wr = &Ws[k * 96 + 6 * fg];
        const f32x2 w01 = *(const f32x2*)(wr);
        const f32x2 w23 = *(const f32x2*)(wr + 2);
        const f32x2 w45 = *(const f32x2*)(wr + 4);
        const float w[6] = {w01[0], w01[1], w23[0], w23[1], w45[0], w45[1]};
#pragma unroll
        for (int nn = 0; nn < 4; ++nn)
#pragma unroll
            for (int ff = 0; ff < 6; ++ff) acc[nn][ff] += a[nn] * w[ff];
    }
    __syncthreads();

#pragma unroll
    for (int nn = 0; nn < 4; ++nn)
#pragma unroll
        for (int ff = 0; ff < 6; ++ff) {
            float v = acc[nn][ff];
            hsT[6 * fg + ff][4 * ng + nn] = v > 0.f ? v : 0.f;
        }
    for (int i = tid; i < 96 * 96 / 4; i += 256)
        ((f32x4*)Ws)[i] = ((const f32x4*)W2g)[i];
    __syncthreads();

#pragma unroll
    for (int ff = 0; ff < 6; ++ff) {
        const float b = b2g[6 * fg + ff];
        acc[0][ff] = b; acc[1][ff] = b; acc[2][ff] = b; acc[3][ff] = b;
    }
    for (int k = 0; k < 96; ++k) {
        const f32x4 a = *(const f32x4*)&hsT[k][4 * ng];
        const float* wr = &Ws[k * 96 + 6 * fg];
        const f32x2 w01 = *(const f32x2*)(wr);
        const f32x2 w23 = *(const f32x2*)(wr + 2);
        const f32x2 w45 = *(const f32x2*)(wr + 4);
        const float w[6] = {w01[0], w01[1], w23[0], w23[1], w45[0], w45[1]};
#pragma unroll
        for (int nn = 0; nn < 4; ++nn)
#pragma unroll
            for (int ff = 0; ff < 6; ++ff) acc[nn][ff] += a[nn] * w[ff];
    }

#pragma unroll
    for (int nn = 0; nn < 4; ++nn) {
        const int n = n0 + 4 * ng + nn;
        if (n < N_NODES) {
            float* o = buf + (size_t)n * 96 + 6 * fg;
            *(f32x2*)(o)     = (f32x2){acc[nn][0], acc[nn][1]};
            *(f32x2*)(o + 2) = (f32x2){acc[nn][2], acc[nn][3]};
            *(f32x2*)(o + 4) = (f32x2){acc[nn][4], acc[nn][5]};
        }
    }

    __syncthreads();
#pragma unroll
    for (int nn = 0; nn < 4; ++nn)
#pragma unroll
        for (int ff = 0; ff < 6; ++ff)
            hsT[6 * fg + ff][4 * ng + nn] = acc[nn][ff];
    __syncthreads();

    if (tid < 96) {
        int nmax = N_NODES - n0;
        if (nmax > MTILE) nmax = MTILE;
        float s = 0.f, s2 = 0.f;
        for (int n = 0; n < nmax; ++n) {
            const float v = hsT[tid][n];
            s += v; s2 += v * v;
        }
        float* st = stats + (blockIdx.x & (NREP - 1)) * 192;
        atomicAdd(&st[tid], s);
        atomicAdd(&st[96 + tid], s2);
    }
}

// ---------------------------------------------------------------------------
// bn: sum stat replicas, finalize + affine + ReLU, float4 streaming.
// ---------------------------------------------------------------------------
__global__ __launch_bounds__(256) void bn_kernel(
    const float* __restrict__ h2, const float* __restrict__ stats,
    const float* __restrict__ gamma, const float* __restrict__ beta,
    float* __restrict__ out) {
    __shared__ float sc[96], sh[96];
    const int tid = threadIdx.x;
    if (tid < 96) {
        float s1 = 0.f, s2 = 0.f;
#pragma unroll
        for (int r = 0; r < NREP; ++r) {
            s1 += stats[r * 192 + tid];
            s2 += stats[r * 192 + 96 + tid];
        }
        const float inv_n = 1.f / (float)N_NODES;
        const float mean = s1 * inv_n;
        float var = s2 * inv_n - mean * mean;
        var = var > 0.f ? var : 0.f;
        const float s = gamma[tid] * rsqrtf(var + BN_EPS);
        sc[tid] = s;
        sh[tid] = beta[tid] - mean * s;
    }
    __syncthreads();
    const int total4 = N_NODES * 96 / 4;
    for (int i = blockIdx.x * blockDim.x + tid; i < total4;
         i += gridDim.x * blockDim.x) {
        f32x4 v = ((const f32x4*)h2)[i];
        const int jb = (i * 4) % 96;
#pragma unroll
        for (int c = 0; c < 4; ++c) {
            float u = v[c] * sc[jb + c] + sh[jb + c];
            v[c] = u > 0.f ? u : 0.f;
        }
        ((f32x4*)out)[i] = v;
    }
}

// ---------------------------------------------------------------------------
extern "C" void kernel_launch(void* const* d_in, const int* in_sizes, int n_in,
                              void* d_out, int out_size, void* d_ws,
                              size_t ws_size, hipStream_t stream) {
    const float* x     = (const float*)d_in[0];
    const int*   ei    = (const int*)d_in[1];
    const float* ea    = (const float*)d_in[2];
    const float* We    = (const float*)d_in[3];
    const float* be    = (const float*)d_in[4];
    const float* W1    = (const float*)d_in[5];
    const float* b1    = (const float*)d_in[6];
    const float* W2    = (const float*)d_in[7];
    const float* b2    = (const float*)d_in[8];
    const float* gamma = (const float*)d_in[9];
    const float* beta  = (const float*)d_in[10];
    float* out = (float*)d_out;

    float* ws    = (float*)d_ws;
    float* hbuf  = ws;
    float* stats = ws + OFF_STATS;
    int*   flagp = (int*)(ws + OFF_FLAG);

    int*  scratch = (int*)d_out;
    int2* pair    = (int2*)(scratch + SC_PAIR);
    int*  lexcl   = scratch + SC_LEXCL;
    int*  deg     = scratch + SC_DEG;
    int*  rank    = scratch + SC_RANK;
    int*  bsum    = scratch + SC_BSUM;

    init_kernel<<<NB_SCAN, 256, 0, stream>>>(ei, flagp, deg, stats);
    hist_kernel<<<1024, 256, 0, stream>>>(ei, flagp, deg, rank);
    scanA_kernel<<<NB_SCAN, 256, 0, stream>>>(deg, lexcl, bsum);
    scatter_kernel<<<1024, 256, 0, stream>>>(ei, flagp, lexcl, bsum, rank, pair);
    // node_aggr split into 4 node-range quarters (instrumentation + balance)
    node_aggr_kernel<<<2048, 256, 0, stream>>>(x, ea, We, be, pair, lexcl,
                                               bsum, hbuf, 0, 12500);
    node_aggr_kernel<<<2048, 256, 0, stream>>>(x, ea, We, be, pair, lexcl,
                                               bsum, hbuf, 12500, 25000);
    node_aggr_kernel<<<2048, 256, 0, stream>>>(x, ea, We, be, pair, lexcl,
                                               bsum, hbuf, 25000, 37500);
    node_aggr_kernel<<<2048, 256, 0, stream>>>(x, ea, We, be, pair, lexcl,
                                               bsum, hbuf, 37500, 50000);
    // mlp split into 2 tile halves
    mlp_kernel<<<NTILES / 2, 256, 0, stream>>>(hbuf, W1, b1, W2, b2, stats, 0);
    mlp_kernel<<<NTILES - NTILES / 2, 256, 0, stream>>>(hbuf, W1, b1, W2, b2,
                                                        stats, NTILES / 2);
    bn_kernel<<<1024, 256, 0, stream>>>(hbuf, stats, gamma, beta, out);
}